// Round 14
// baseline (212.622 us; speedup 1.0000x reference)
//
#include <hip/hip_runtime.h>

typedef _Float16 h4 __attribute__((ext_vector_type(4)));
typedef _Float16 h8v __attribute__((ext_vector_type(8)));
typedef float f4v __attribute__((ext_vector_type(4)));
typedef float f32x8 __attribute__((ext_vector_type(8)));

// ---------------- CSR construction ----------------

__global__ void zero_i32(int* __restrict__ p, int n) {
    int i = blockIdx.x * blockDim.x + threadIdx.x;
    if (i < n) p[i] = 0;
}

// per-block exclusive scan into rowptrL + block sums; also zeros cursor
__global__ void scan_block(const int* __restrict__ counts, int* __restrict__ rowptrL,
                           int* __restrict__ bsum, int* __restrict__ cursor, int n) {
    __shared__ int wsum[16];
    const int tid = threadIdx.x;           // blockDim.x == 1024
    const int lane = tid & 63, wv = tid >> 6;
    const int i = blockIdx.x * 1024 + tid;
    if (i < n) cursor[i] = 0;
    int v = (i < n) ? counts[i] : 0;
    int x = v;
#pragma unroll
    for (int off = 1; off < 64; off <<= 1) {
        int t = __shfl_up(x, off);
        if (lane >= off) x += t;
    }
    if (lane == 63) wsum[wv] = x;
    __syncthreads();
    if (tid < 16) {
        int y = wsum[tid];
#pragma unroll
        for (int off = 1; off < 16; off <<= 1) {
            int t = __shfl_up(y, off);
            if (tid >= off) y += t;
        }
        wsum[tid] = y;
    }
    __syncthreads();
    int woff = (wv > 0) ? wsum[wv - 1] : 0;
    if (i < n) rowptrL[i] = woff + x - v;   // block-local exclusive
    if (tid == 0) bsum[blockIdx.x] = wsum[15];
}

// merged: scatter (using block-local rowptr + in-wave bsum prefix) and
// global-rowptr finalize (separate output array -> no race).
__global__ __launch_bounds__(256)
void scan_scatter(const int* __restrict__ rowptrL, const int* __restrict__ bsum,
                  int* __restrict__ rowptrG, const int* __restrict__ src,
                  const int* __restrict__ dst, int* __restrict__ cursor,
                  int* __restrict__ srcs, int nb, int n, int E, int SB) {
    __shared__ int pref[64];
    __shared__ int tot_s;
    const int tid = threadIdx.x;
    if (tid < 64) {
        int v = (tid < nb) ? bsum[tid] : 0;
        int x = v;
#pragma unroll
        for (int off = 1; off < 64; off <<= 1) {
            int t = __shfl_up(x, off);
            if (tid >= off) x += t;
        }
        pref[tid] = x - v;                 // exclusive block prefix
        if (tid == 63) tot_s = x;          // grand total
    }
    __syncthreads();
    const int b = blockIdx.x;
    if (b < SB) {                          // ---- scatter region ----
        int i = b * 256 + tid;
        if (i < E) {
            int d = dst[i];
            int p = pref[d >> 10] + rowptrL[d] + atomicAdd(&cursor[d], 1);
            srcs[p] = src[i];
        }
    } else {                               // ---- rowptrG finalize ----
        int i = (b - SB) * 256 + tid;
        if (i < n) rowptrG[i] = rowptrL[i] + pref[i >> 10];
        if (i == 0) rowptrG[n] = tot_s;
    }
}

// ---------------- fused front: hist + W-pack + layer-1 GEMM ----------------
__global__ __launch_bounds__(256)
void fused_front(const int* __restrict__ dst, int* __restrict__ counts, int E,
                 const float* __restrict__ W2, _Float16* __restrict__ Wp2,
                 const float* __restrict__ W3, _Float16* __restrict__ Wp3,
                 const float* __restrict__ A, const float* __restrict__ W1,
                 const float* __restrict__ al, const float* __restrict__ ar,
                 _Float16* __restrict__ feat, float* __restrict__ el,
                 float* __restrict__ er, int N, int HB, int PB) {
    const int b = blockIdx.x;
    if (b < HB) {                          // ---- histogram ----
        int i = b * 256 + threadIdx.x;
        if (i < E) atomicAdd(&counts[dst[i]], 1);
        return;
    }
    if (b < HB + PB) {                     // ---- W pre-pack (B-frag order) ----
        int idx = (b - HB) * 256 + threadIdx.x;
        const float* W; _Float16* Wp; int FOUT;
        if (idx < 2048) { W = W2; Wp = Wp2; FOUT = 128; }
        else {
            idx -= 2048;
            if (idx >= 4096) return;
            W = W3; Wp = Wp3; FOUT = 256;
        }
        int l = idx & 63;
        int ks = (idx >> 6) & 3;
        int ct = idx >> 8;
        int kbase = ks * 32 + (l >> 4) * 8;
        int col = ct * 16 + (l & 15);
        h8v v;
#pragma unroll
        for (int e = 0; e < 8; e++) v[e] = (_Float16)W[(size_t)(kbase + e) * FOUT + col];
        *reinterpret_cast<h8v*>(&Wp[(size_t)idx * 8]) = v;
        return;
    }
    // ---- layer-1 GEMM + el/er (FIN=6, FOUT=128, D=32) ----
    constexpr int FIN = 6, FOUT = 128, D = 32, R = 16, H = 4, T = 64;
    __shared__ __align__(16) float As[4][FIN][R + 4];
    const int sub = threadIdx.x >> 6;      // wave within block = row sub-tile
    const int j = threadIdx.x & 63;
    const int h0 = j / D;
    const int h1 = (j + T) / D;
    const float alv0 = al[j],     arv0 = ar[j];
    const float alv1 = al[j + T], arv1 = ar[j + T];
    const int row0 = (b - HB - PB) * 64 + sub * R;

    for (int idx = j; idx < R * FIN; idx += T) {
        int r = idx / FIN, k = idx % FIN;
        int rr = row0 + r;
        As[sub][k][r] = (rr < N) ? A[(size_t)rr * FIN + k] : 0.f;
    }
    __syncthreads();

    float acc0[R], acc1[R];
#pragma unroll
    for (int r = 0; r < R; r++) { acc0[r] = 0.f; acc1[r] = 0.f; }

    for (int k = 0; k < FIN; k++) {
        float w0 = W1[(size_t)k * FOUT + j];
        float w1 = W1[(size_t)k * FOUT + j + T];
        const float4* ap = reinterpret_cast<const float4*>(&As[sub][k][0]);
        float av[16];
        *reinterpret_cast<float4*>(&av[0])  = ap[0];
        *reinterpret_cast<float4*>(&av[4])  = ap[1];
        *reinterpret_cast<float4*>(&av[8])  = ap[2];
        *reinterpret_cast<float4*>(&av[12]) = ap[3];
#pragma unroll
        for (int r = 0; r < R; r++) {
            acc0[r] += av[r] * w0;
            acc1[r] += av[r] * w1;
        }
    }

#pragma unroll
    for (int r = 0; r < R; r++) {
        int rr = row0 + r;
        if (rr >= N) break;                // uniform per wave; no barriers below
        float v0 = acc0[r], v1 = acc1[r];
        feat[(size_t)rr * FOUT + j] = (_Float16)v0;
        feat[(size_t)rr * FOUT + j + T] = (_Float16)v1;
        float vl0 = v0 * alv0, vr0 = v0 * arv0;
        float vl1 = v1 * alv1, vr1 = v1 * arv1;
#pragma unroll
        for (int off = D / 2; off >= 1; off >>= 1) {
            vl0 += __shfl_xor(vl0, off);
            vr0 += __shfl_xor(vr0, off);
            vl1 += __shfl_xor(vl1, off);
            vr1 += __shfl_xor(vr1, off);
        }
        if ((j % D) == 0) {
            el[(size_t)rr * H + h0] = vl0;
            er[(size_t)rr * H + h0] = vr0;
            el[(size_t)rr * H + h1] = vl1;
            er[(size_t)rr * H + h1] = vr1;
        }
    }
}

// ---------------- layers 2/3: MFMA fp16 GEMM + fused el/er ----------------
template <int K, int FOUT, int D>
__global__ __launch_bounds__(256)
void gemm_mfma(const _Float16* __restrict__ A, const _Float16* __restrict__ Wp,
               const float* __restrict__ al, const float* __restrict__ ar,
               _Float16* __restrict__ feat, float* __restrict__ el,
               float* __restrict__ er, int N) {
    constexpr int RB  = 32;
    constexpr int KS  = K / 32;
    constexpr int CHW = FOUT / 2;
    constexpr int CTW = CHW / 16;
    constexpr int CTH = D / 16;
    constexpr int HW  = CTW / CTH;
    constexpr int H   = FOUT / D;
    constexpr int STR = K + 8;
    __shared__ _Float16 As[RB * STR];
    const int tid = threadIdx.x;
    const int w  = tid >> 6;
    const int l  = tid & 63;
    const int rt = w >> 1;
    const int ch = w & 1;
    const int row0 = blockIdx.x * RB;

    constexpr int NV8 = RB * K / 8;
    for (int v = tid; v < NV8; v += 256) {
        int r  = v / (K / 8);
        int kv = (v % (K / 8)) * 8;
        int rr = row0 + r;
        h8v x = {};
        if (rr < N) x = *reinterpret_cast<const h8v*>(&A[(size_t)rr * K + kv]);
        *reinterpret_cast<h8v*>(&As[r * STR + kv]) = x;
    }
    __syncthreads();

    h8v afrag[KS];
    {
        const _Float16* base = &As[(rt * 16 + (l & 15)) * STR + ((l >> 4) * 8)];
#pragma unroll
        for (int ks = 0; ks < KS; ks++)
            afrag[ks] = *reinterpret_cast<const h8v*>(&base[ks * 32]);
    }

    const h8v* Wv = reinterpret_cast<const h8v*>(Wp);
    const int ct0 = ch * CTW;
    f4v acc[CTW];
#pragma unroll
    for (int c = 0; c < CTW; c++) acc[c] = (f4v){0.f, 0.f, 0.f, 0.f};

    h8v bfr[2][KS];
#pragma unroll
    for (int ks = 0; ks < KS; ks++) bfr[0][ks] = Wv[(size_t)((ct0 * KS + ks) * 64 + l)];
#pragma unroll
    for (int c = 0; c < CTW; c++) {
        const int cur = c & 1, nxt = cur ^ 1;
        if (c + 1 < CTW) {
#pragma unroll
            for (int ks = 0; ks < KS; ks++)
                bfr[nxt][ks] = Wv[(size_t)(((ct0 + c + 1) * KS + ks) * 64 + l)];
        }
#pragma unroll
        for (int ks = 0; ks < KS; ks++)
            acc[c] = __builtin_amdgcn_mfma_f32_16x16x32_f16(afrag[ks], bfr[cur][ks], acc[c], 0, 0, 0);
    }

    float elp[HW][4], erp[HW][4];
#pragma unroll
    for (int hh = 0; hh < HW; hh++)
#pragma unroll
        for (int r = 0; r < 4; r++) { elp[hh][r] = 0.f; erp[hh][r] = 0.f; }

#pragma unroll
    for (int c = 0; c < CTW; c++) {
        const int col = ch * CHW + c * 16 + (l & 15);
        const float alv = al[col], arv = ar[col];
        const int hh = c / CTH;
#pragma unroll
        for (int r = 0; r < 4; r++) {
            float v = acc[c][r];
            elp[hh][r] += v * alv;
            erp[hh][r] += v * arv;
            int rr = row0 + rt * 16 + (l >> 4) * 4 + r;
            if (rr < N) feat[(size_t)rr * FOUT + col] = (_Float16)v;
        }
    }
#pragma unroll
    for (int hh = 0; hh < HW; hh++) {
#pragma unroll
        for (int r = 0; r < 4; r++) {
            float v = elp[hh][r], u = erp[hh][r];
#pragma unroll
            for (int off = 8; off >= 1; off >>= 1) {
                v += __shfl_xor(v, off);
                u += __shfl_xor(u, off);
            }
            if ((l & 15) == 0) {
                int rr = row0 + rt * 16 + (l >> 4) * 4 + r;
                if (rr < N) {
                    int hg = ch * HW + hh;
                    el[(size_t)rr * H + hg] = v;
                    er[(size_t)rr * H + hg] = u;
                }
            }
        }
    }
}

// ---------------- subgroup-parallel edge softmax + aggregation ----------------
// Half-channel pass: gathers only CH of the HD channels (chbase..chbase+CH-1).
// Two sequential dispatches per layer -> per-pass table footprint halves and
// (layers 1/2) fits per-XCD L2. Heads live entirely inside one half, so no
// duplicated exp/sum work. Pipelined phase-1 (next chunk's srcs/el/exp issue
// before this chunk's FMAs). No max-subtraction (identical math; logits
// O(+-10), fp32 exp safe).
template <int HD, int D, int CH, bool FP16OUT>
__global__ __launch_bounds__(256)
void agg_sub(const h8v* __restrict__ featH8, const float* __restrict__ el,
             const float* __restrict__ er, const int* __restrict__ srcs,
             const int* __restrict__ rowptr, const float* __restrict__ bias,
             void* __restrict__ outp, int N, int chbase) {
    constexpr int TPN = CH / 8;          // lanes per node this pass (8 or 16)
    constexpr int NPB = 256 / TPN;       // nodes per block (32 or 16)
    constexpr int SG  = D / 8;           // lanes per head subgroup: 4 or 8
    constexpr int RSTR = HD / 8;         // h8v per full feat row
    const int tid = threadIdx.x;
    const int ln  = tid % TPN;           // lane within node (this pass)
    const int q   = ln % SG;             // lane within head subgroup
    const int node = blockIdx.x * NPB + tid / TPN;
    if (node >= N) return;
    const int h = (chbase + ln * 8) / D; // head of this lane's 8 channels
    const int beg = rowptr[node], end = rowptr[node + 1];
    const float ern = er[(size_t)node * 4 + h];
    const h8v* frow = featH8 + (chbase >> 3) + ln;

    float s = 0.f;
    f32x8 a0 = {0,0,0,0,0,0,0,0}, a1 = a0;

    if (beg < end) {
        // prologue: phase 1 for chunk at beg
        int idx = beg + q;
        int u_q = srcs[idx < end ? idx : end - 1];
        float x = el[(size_t)u_q * 4 + h] + ern;
        x = x > 0.f ? x : 0.2f * x;
        float w_q = (idx < end) ? __expf(x) : 0.f;

        for (int i = beg; i < end; ) {
            const int inext = i + SG;
            // phase 1 of next chunk: loads issue before this chunk's FMAs
            int u_n = 0; float w_n = 0.f;
            if (inext < end) {
                int idx2 = inext + q;
                int u2 = srcs[idx2 < end ? idx2 : end - 1];
                float x2 = el[(size_t)u2 * 4 + h] + ern;
                x2 = x2 > 0.f ? x2 : 0.2f * x2;
                w_n = (idx2 < end) ? __expf(x2) : 0.f;
                u_n = u2;
            }
            s += w_q;
            // phase 2: broadcast within subgroup; coalesced gathers + FMA
#pragma unroll
            for (int j = 0; j < SG; j += 2) {
                int   u0 = __shfl(u_q, j, SG);
                float w0 = __shfl(w_q, j, SG);
                int   u1 = __shfl(u_q, j + 1, SG);
                float w1 = __shfl(w_q, j + 1, SG);
                h8v f0 = frow[(size_t)u0 * RSTR];
                h8v f1 = frow[(size_t)u1 * RSTR];
#pragma unroll
                for (int k = 0; k < 8; k++) {
                    a0[k] += w0 * (float)f0[k];
                    a1[k] += w1 * (float)f1[k];
                }
            }
            i = inext; u_q = u_n; w_q = w_n;
        }
    }
    // reduce s over the subgroup (each edge counted exactly once)
#pragma unroll
    for (int off = SG / 2; off >= 1; off >>= 1) s += __shfl_xor(s, off);
    const float inv = (s > 0.f) ? 1.f / s : 0.f;

    if constexpr (FP16OUT) {
        const float4 b0 = *reinterpret_cast<const float4*>(&bias[chbase + ln * 8]);
        const float4 b1v = *reinterpret_cast<const float4*>(&bias[chbase + ln * 8 + 4]);
        float bb[8] = {b0.x, b0.y, b0.z, b0.w, b1v.x, b1v.y, b1v.z, b1v.w};
        h8v o;
#pragma unroll
        for (int k = 0; k < 8; k++)
            o[k] = (_Float16)fmaxf((a0[k] + a1[k]) * inv + bb[k], 0.f);
        reinterpret_cast<h8v*>(outp)[(size_t)node * RSTR + (chbase >> 3) + ln] = o;
    } else {
        h8v o;                           // fp16 out, bias added in readout
#pragma unroll
        for (int k = 0; k < 8; k++) o[k] = (_Float16)((a0[k] + a1[k]) * inv);
        reinterpret_cast<h8v*>(outp)[(size_t)node * RSTR + (chbase >> 3) + ln] = o;
    }
}

// ---------------- batched-graph mean readout (two-phase, fp16 input) --------

__device__ __forceinline__ int lower_bound_i(const int* __restrict__ a, int n, int key) {
    int lo = 0, hi = n;
    while (lo < hi) {
        int mid = (lo + hi) >> 1;
        if (a[mid] < key) lo = mid + 1; else hi = mid;
    }
    return lo;
}

__global__ void readout_partial(const _Float16* __restrict__ agg, const int* __restrict__ gid,
                                float* __restrict__ part, int N, int C, int SL) {
    int g = blockIdx.x / SL, slice = blockIdx.x % SL;
    int c = threadIdx.x;
    int start = lower_bound_i(gid, N, g);
    int end = lower_bound_i(gid, N, g + 1);
    float sum = 0.f;
    for (int n = start + slice; n < end; n += SL) sum += (float)agg[(size_t)n * C + c];
    part[((size_t)g * SL + slice) * C + c] = sum;
}

__global__ void readout_final(const float* __restrict__ part, const float* __restrict__ b3,
                              const int* __restrict__ gid, float* __restrict__ out,
                              int N, int C, int SL) {
    int g = blockIdx.x, c = threadIdx.x;
    int start = lower_bound_i(gid, N, g);
    int end = lower_bound_i(gid, N, g + 1);
    int cnt = end - start;
    float s = 0.f;
    for (int k = 0; k < SL; k++) s += part[((size_t)g * SL + k) * C + c];
    out[(size_t)g * C + c] = (cnt > 0) ? s / (float)cnt + b3[c] : 0.f;
}

// ---------------- launch ----------------

extern "C" void kernel_launch(void* const* d_in, const int* in_sizes, int n_in,
                              void* d_out, int out_size, void* d_ws, size_t ws_size,
                              hipStream_t stream) {
    const float* feat0 = (const float*)d_in[0];
    const int* src = (const int*)d_in[1];
    const int* dst = (const int*)d_in[2];
    const int* gid = (const int*)d_in[3];
    const float* W1 = (const float*)d_in[4];
    const float* al1 = (const float*)d_in[5];
    const float* ar1 = (const float*)d_in[6];
    const float* b1 = (const float*)d_in[7];
    const float* W2 = (const float*)d_in[8];
    const float* al2 = (const float*)d_in[9];
    const float* ar2 = (const float*)d_in[10];
    const float* b2 = (const float*)d_in[11];
    const float* W3 = (const float*)d_in[12];
    const float* al3 = (const float*)d_in[13];
    const float* ar3 = (const float*)d_in[14];
    const float* b3 = (const float*)d_in[15];

    const int N = in_sizes[0] / 6;       // 30000
    const int E = in_sizes[1];           // 480000
    const int G = 64;
    const int SL = 16;
    float* out = (float*)d_out;

    char* wsp = (char*)d_ws;
    auto alloc = [&](size_t bytes) -> char* {
        char* p = wsp;
        wsp += (bytes + 255) & ~(size_t)255;
        return p;
    };
    int* counts   = (int*)alloc((size_t)N * 4);
    int* rowptrL  = (int*)alloc((size_t)(N + 1) * 4);
    int* rowptrG  = (int*)alloc((size_t)(N + 1) * 4);
    int* cursor   = (int*)alloc((size_t)N * 4);
    int* bsum     = (int*)alloc(64 * 4);
    int* srcs     = (int*)alloc((size_t)E * 4);
    float* el     = (float*)alloc((size_t)N * 4 * 4);
    float* er     = (float*)alloc((size_t)N * 4 * 4);
    _Float16* featH = (_Float16*)alloc((size_t)N * 256 * 2);  // GEMM out (gathered)
    _Float16* aggH  = (_Float16*)alloc((size_t)N * 128 * 2);  // activated agg out
    _Float16* aggF  = (_Float16*)alloc((size_t)N * 256 * 2);  // layer-3 agg (fp16)
    float* part   = (float*)alloc((size_t)G * SL * 256 * 4);
    _Float16* Wp2 = (_Float16*)alloc((size_t)128 * 128 * 2);
    _Float16* Wp3 = (_Float16*)alloc((size_t)128 * 256 * 2);

    const int nb = (N + 1023) / 1024;    // scan blocks (30)
    const int HB = (E + 255) / 256;      // hist blocks
    const int PB = 24;                   // pack blocks
    const int CB = (N + 63) / 64;        // layer-1 gemm blocks
    const int SB = (E + 255) / 256;      // scatter blocks
    const int AB = (N + 255) / 256;      // rowptrG finalize blocks

    // CSR build + front fusion
    zero_i32<<<dim3((N + 255) / 256), dim3(256), 0, stream>>>(counts, N);
    fused_front<<<dim3(HB + PB + CB), dim3(256), 0, stream>>>(
        dst, counts, E, W2, Wp2, W3, Wp3, feat0, W1, al1, ar1, featH, el, er, N, HB, PB);
    scan_block<<<dim3(nb), dim3(1024), 0, stream>>>(counts, rowptrL, bsum, cursor, N);
    scan_scatter<<<dim3(SB + AB), dim3(256), 0, stream>>>(
        rowptrL, bsum, rowptrG, src, dst, cursor, srcs, nb, N, E, SB);

    // layer 1 agg (two sequential half-channel passes, table half L2-fits)
    agg_sub<128, 32, 64, true><<<dim3((N + 31) / 32), dim3(256), 0, stream>>>(
        (const h8v*)featH, el, er, srcs, rowptrG, b1, aggH, N, 0);
    agg_sub<128, 32, 64, true><<<dim3((N + 31) / 32), dim3(256), 0, stream>>>(
        (const h8v*)featH, el, er, srcs, rowptrG, b1, aggH, N, 64);

    // layer 2
    gemm_mfma<128, 128, 32><<<dim3((N + 31) / 32), dim3(256), 0, stream>>>(
        aggH, Wp2, al2, ar2, featH, el, er, N);
    agg_sub<128, 32, 64, true><<<dim3((N + 31) / 32), dim3(256), 0, stream>>>(
        (const h8v*)featH, el, er, srcs, rowptrG, b2, aggH, N, 0);
    agg_sub<128, 32, 64, true><<<dim3((N + 31) / 32), dim3(256), 0, stream>>>(
        (const h8v*)featH, el, er, srcs, rowptrG, b2, aggH, N, 64);

    // layer 3
    gemm_mfma<128, 256, 64><<<dim3((N + 31) / 32), dim3(256), 0, stream>>>(
        aggH, Wp3, al3, ar3, featH, el, er, N);
    agg_sub<256, 64, 128, false><<<dim3((N + 15) / 16), dim3(256), 0, stream>>>(
        (const h8v*)featH, el, er, srcs, rowptrG, nullptr, aggF, N, 0);
    agg_sub<256, 64, 128, false><<<dim3((N + 15) / 16), dim3(256), 0, stream>>>(
        (const h8v*)featH, el, er, srcs, rowptrG, nullptr, aggF, N, 128);

    // readout (fp16 in, bias fp32 in final)
    readout_partial<<<dim3(G * SL), dim3(256), 0, stream>>>(aggF, gid, part, N, 256, SL);
    readout_final<<<dim3(G), dim3(256), 0, stream>>>(part, b3, gid, out, N, 256, SL);
}

// Round 15
// 202.778 us; speedup vs baseline: 1.0485x; 1.0485x over previous
//
#include <hip/hip_runtime.h>

typedef _Float16 h4 __attribute__((ext_vector_type(4)));
typedef _Float16 h8v __attribute__((ext_vector_type(8)));
typedef float f4v __attribute__((ext_vector_type(4)));
typedef float f32x8 __attribute__((ext_vector_type(8)));

// ---------------- CSR construction ----------------

__global__ void zero_i32(int* __restrict__ p, int n) {
    int i = blockIdx.x * blockDim.x + threadIdx.x;
    if (i < n) p[i] = 0;
}

// per-block exclusive scan into rowptrL + block sums; also zeros cursor
__global__ void scan_block(const int* __restrict__ counts, int* __restrict__ rowptrL,
                           int* __restrict__ bsum, int* __restrict__ cursor, int n) {
    __shared__ int wsum[16];
    const int tid = threadIdx.x;           // blockDim.x == 1024
    const int lane = tid & 63, wv = tid >> 6;
    const int i = blockIdx.x * 1024 + tid;
    if (i < n) cursor[i] = 0;
    int v = (i < n) ? counts[i] : 0;
    int x = v;
#pragma unroll
    for (int off = 1; off < 64; off <<= 1) {
        int t = __shfl_up(x, off);
        if (lane >= off) x += t;
    }
    if (lane == 63) wsum[wv] = x;
    __syncthreads();
    if (tid < 16) {
        int y = wsum[tid];
#pragma unroll
        for (int off = 1; off < 16; off <<= 1) {
            int t = __shfl_up(y, off);
            if (tid >= off) y += t;
        }
        wsum[tid] = y;
    }
    __syncthreads();
    int woff = (wv > 0) ? wsum[wv - 1] : 0;
    if (i < n) rowptrL[i] = woff + x - v;   // block-local exclusive
    if (tid == 0) bsum[blockIdx.x] = wsum[15];
}

// merged: scatter (using block-local rowptr + in-wave bsum prefix) and
// global-rowptr finalize (separate output array -> no race).
__global__ __launch_bounds__(256)
void scan_scatter(const int* __restrict__ rowptrL, const int* __restrict__ bsum,
                  int* __restrict__ rowptrG, const int* __restrict__ src,
                  const int* __restrict__ dst, int* __restrict__ cursor,
                  int* __restrict__ srcs, int nb, int n, int E, int SB) {
    __shared__ int pref[64];
    __shared__ int tot_s;
    const int tid = threadIdx.x;
    if (tid < 64) {
        int v = (tid < nb) ? bsum[tid] : 0;
        int x = v;
#pragma unroll
        for (int off = 1; off < 64; off <<= 1) {
            int t = __shfl_up(x, off);
            if (tid >= off) x += t;
        }
        pref[tid] = x - v;                 // exclusive block prefix
        if (tid == 63) tot_s = x;          // grand total
    }
    __syncthreads();
    const int b = blockIdx.x;
    if (b < SB) {                          // ---- scatter region ----
        int i = b * 256 + tid;
        if (i < E) {
            int d = dst[i];
            int p = pref[d >> 10] + rowptrL[d] + atomicAdd(&cursor[d], 1);
            srcs[p] = src[i];
        }
    } else {                               // ---- rowptrG finalize ----
        int i = (b - SB) * 256 + tid;
        if (i < n) rowptrG[i] = rowptrL[i] + pref[i >> 10];
        if (i == 0) rowptrG[n] = tot_s;
    }
}

// ---------------- fused front: hist + W-pack + layer-1 GEMM ----------------
__global__ __launch_bounds__(256)
void fused_front(const int* __restrict__ dst, int* __restrict__ counts, int E,
                 const float* __restrict__ W2, _Float16* __restrict__ Wp2,
                 const float* __restrict__ W3, _Float16* __restrict__ Wp3,
                 const float* __restrict__ A, const float* __restrict__ W1,
                 const float* __restrict__ al, const float* __restrict__ ar,
                 _Float16* __restrict__ feat, float* __restrict__ el,
                 float* __restrict__ er, int N, int HB, int PB) {
    const int b = blockIdx.x;
    if (b < HB) {                          // ---- histogram ----
        int i = b * 256 + threadIdx.x;
        if (i < E) atomicAdd(&counts[dst[i]], 1);
        return;
    }
    if (b < HB + PB) {                     // ---- W pre-pack (B-frag order) ----
        int idx = (b - HB) * 256 + threadIdx.x;
        const float* W; _Float16* Wp; int FOUT;
        if (idx < 2048) { W = W2; Wp = Wp2; FOUT = 128; }
        else {
            idx -= 2048;
            if (idx >= 4096) return;
            W = W3; Wp = Wp3; FOUT = 256;
        }
        int l = idx & 63;
        int ks = (idx >> 6) & 3;
        int ct = idx >> 8;
        int kbase = ks * 32 + (l >> 4) * 8;
        int col = ct * 16 + (l & 15);
        h8v v;
#pragma unroll
        for (int e = 0; e < 8; e++) v[e] = (_Float16)W[(size_t)(kbase + e) * FOUT + col];
        *reinterpret_cast<h8v*>(&Wp[(size_t)idx * 8]) = v;
        return;
    }
    // ---- layer-1 GEMM + el/er (FIN=6, FOUT=128, D=32) ----
    constexpr int FIN = 6, FOUT = 128, D = 32, R = 16, H = 4, T = 64;
    __shared__ __align__(16) float As[4][FIN][R + 4];
    const int sub = threadIdx.x >> 6;      // wave within block = row sub-tile
    const int j = threadIdx.x & 63;
    const int h0 = j / D;
    const int h1 = (j + T) / D;
    const float alv0 = al[j],     arv0 = ar[j];
    const float alv1 = al[j + T], arv1 = ar[j + T];
    const int row0 = (b - HB - PB) * 64 + sub * R;

    for (int idx = j; idx < R * FIN; idx += T) {
        int r = idx / FIN, k = idx % FIN;
        int rr = row0 + r;
        As[sub][k][r] = (rr < N) ? A[(size_t)rr * FIN + k] : 0.f;
    }
    __syncthreads();

    float acc0[R], acc1[R];
#pragma unroll
    for (int r = 0; r < R; r++) { acc0[r] = 0.f; acc1[r] = 0.f; }

    for (int k = 0; k < FIN; k++) {
        float w0 = W1[(size_t)k * FOUT + j];
        float w1 = W1[(size_t)k * FOUT + j + T];
        const float4* ap = reinterpret_cast<const float4*>(&As[sub][k][0]);
        float av[16];
        *reinterpret_cast<float4*>(&av[0])  = ap[0];
        *reinterpret_cast<float4*>(&av[4])  = ap[1];
        *reinterpret_cast<float4*>(&av[8])  = ap[2];
        *reinterpret_cast<float4*>(&av[12]) = ap[3];
#pragma unroll
        for (int r = 0; r < R; r++) {
            acc0[r] += av[r] * w0;
            acc1[r] += av[r] * w1;
        }
    }

#pragma unroll
    for (int r = 0; r < R; r++) {
        int rr = row0 + r;
        if (rr >= N) break;                // uniform per wave; no barriers below
        float v0 = acc0[r], v1 = acc1[r];
        feat[(size_t)rr * FOUT + j] = (_Float16)v0;
        feat[(size_t)rr * FOUT + j + T] = (_Float16)v1;
        float vl0 = v0 * alv0, vr0 = v0 * arv0;
        float vl1 = v1 * alv1, vr1 = v1 * arv1;
#pragma unroll
        for (int off = D / 2; off >= 1; off >>= 1) {
            vl0 += __shfl_xor(vl0, off);
            vr0 += __shfl_xor(vr0, off);
            vl1 += __shfl_xor(vl1, off);
            vr1 += __shfl_xor(vr1, off);
        }
        if ((j % D) == 0) {
            el[(size_t)rr * H + h0] = vl0;
            er[(size_t)rr * H + h0] = vr0;
            el[(size_t)rr * H + h1] = vl1;
            er[(size_t)rr * H + h1] = vr1;
        }
    }
}

// ---------------- layers 2/3: MFMA fp16 GEMM + fused el/er ----------------
template <int K, int FOUT, int D>
__global__ __launch_bounds__(256)
void gemm_mfma(const _Float16* __restrict__ A, const _Float16* __restrict__ Wp,
               const float* __restrict__ al, const float* __restrict__ ar,
               _Float16* __restrict__ feat, float* __restrict__ el,
               float* __restrict__ er, int N) {
    constexpr int RB  = 32;
    constexpr int KS  = K / 32;
    constexpr int CHW = FOUT / 2;
    constexpr int CTW = CHW / 16;
    constexpr int CTH = D / 16;
    constexpr int HW  = CTW / CTH;
    constexpr int H   = FOUT / D;
    constexpr int STR = K + 8;
    __shared__ _Float16 As[RB * STR];
    const int tid = threadIdx.x;
    const int w  = tid >> 6;
    const int l  = tid & 63;
    const int rt = w >> 1;
    const int ch = w & 1;
    const int row0 = blockIdx.x * RB;

    constexpr int NV8 = RB * K / 8;
    for (int v = tid; v < NV8; v += 256) {
        int r  = v / (K / 8);
        int kv = (v % (K / 8)) * 8;
        int rr = row0 + r;
        h8v x = {};
        if (rr < N) x = *reinterpret_cast<const h8v*>(&A[(size_t)rr * K + kv]);
        *reinterpret_cast<h8v*>(&As[r * STR + kv]) = x;
    }
    __syncthreads();

    h8v afrag[KS];
    {
        const _Float16* base = &As[(rt * 16 + (l & 15)) * STR + ((l >> 4) * 8)];
#pragma unroll
        for (int ks = 0; ks < KS; ks++)
            afrag[ks] = *reinterpret_cast<const h8v*>(&base[ks * 32]);
    }

    const h8v* Wv = reinterpret_cast<const h8v*>(Wp);
    const int ct0 = ch * CTW;
    f4v acc[CTW];
#pragma unroll
    for (int c = 0; c < CTW; c++) acc[c] = (f4v){0.f, 0.f, 0.f, 0.f};

    h8v bfr[2][KS];
#pragma unroll
    for (int ks = 0; ks < KS; ks++) bfr[0][ks] = Wv[(size_t)((ct0 * KS + ks) * 64 + l)];
#pragma unroll
    for (int c = 0; c < CTW; c++) {
        const int cur = c & 1, nxt = cur ^ 1;
        if (c + 1 < CTW) {
#pragma unroll
            for (int ks = 0; ks < KS; ks++)
                bfr[nxt][ks] = Wv[(size_t)(((ct0 + c + 1) * KS + ks) * 64 + l)];
        }
#pragma unroll
        for (int ks = 0; ks < KS; ks++)
            acc[c] = __builtin_amdgcn_mfma_f32_16x16x32_f16(afrag[ks], bfr[cur][ks], acc[c], 0, 0, 0);
    }

    float elp[HW][4], erp[HW][4];
#pragma unroll
    for (int hh = 0; hh < HW; hh++)
#pragma unroll
        for (int r = 0; r < 4; r++) { elp[hh][r] = 0.f; erp[hh][r] = 0.f; }

#pragma unroll
    for (int c = 0; c < CTW; c++) {
        const int col = ch * CHW + c * 16 + (l & 15);
        const float alv = al[col], arv = ar[col];
        const int hh = c / CTH;
#pragma unroll
        for (int r = 0; r < 4; r++) {
            float v = acc[c][r];
            elp[hh][r] += v * alv;
            erp[hh][r] += v * arv;
            int rr = row0 + rt * 16 + (l >> 4) * 4 + r;
            if (rr < N) feat[(size_t)rr * FOUT + col] = (_Float16)v;
        }
    }
#pragma unroll
    for (int hh = 0; hh < HW; hh++) {
#pragma unroll
        for (int r = 0; r < 4; r++) {
            float v = elp[hh][r], u = erp[hh][r];
#pragma unroll
            for (int off = 8; off >= 1; off >>= 1) {
                v += __shfl_xor(v, off);
                u += __shfl_xor(u, off);
            }
            if ((l & 15) == 0) {
                int rr = row0 + rt * 16 + (l >> 4) * 4 + r;
                if (rr < N) {
                    int hg = ch * HW + hh;
                    el[(size_t)rr * H + hg] = v;
                    er[(size_t)rr * H + hg] = u;
                }
            }
        }
    }
}

// ---------------- subgroup-parallel edge softmax + aggregation ----------------
// Full-row coalesced gathers (TPN lanes per node). SG lanes of a head-subgroup
// each weight a different edge (1 el gather + 1 exp per edge per subgroup),
// shfl-broadcast (u,w). Phase 2 issues 4 independent row-gathers before any
// FMA (deeper MLP). Phase-1 of chunk i+1 is software-pipelined ahead of chunk
// i's FMA body. No max-subtraction (identical math; logits O(+-10), fp32 exp
// safe). Accumulator pairing (even j -> a0, odd j -> a1) matches prior rounds,
// so numerics are bit-identical.
template <int HD, int D, bool FP16OUT>
__global__ __launch_bounds__(256)
void agg_sub(const h8v* __restrict__ featH8, const float* __restrict__ el,
             const float* __restrict__ er, const int* __restrict__ srcs,
             const int* __restrict__ rowptr, const float* __restrict__ bias,
             void* __restrict__ outp, int N) {
    constexpr int TPN = HD / 8;          // 16 or 32 lanes per node
    constexpr int NPB = 256 / TPN;       // 16 or 8 nodes per block
    constexpr int SG  = D / 8;           // lanes per head subgroup: 4 or 8
    constexpr int RSTR = HD / 8;         // h8v per feat row
    const int tid = threadIdx.x;
    const int ln  = tid % TPN;           // lane within node
    const int q   = ln % SG;             // lane within head subgroup
    const int h   = ln / SG;             // head (0..3)
    const int node = blockIdx.x * NPB + tid / TPN;
    if (node >= N) return;
    const int beg = rowptr[node], end = rowptr[node + 1];
    const float ern = er[(size_t)node * 4 + h];
    const h8v* frow = featH8 + ln;

    float s = 0.f;
    f32x8 a0 = {0,0,0,0,0,0,0,0}, a1 = a0;

    if (beg < end) {
        // prologue: phase 1 for chunk at beg
        int idx = beg + q;
        int u_q = srcs[idx < end ? idx : end - 1];
        float x = el[(size_t)u_q * 4 + h] + ern;
        x = x > 0.f ? x : 0.2f * x;
        float w_q = (idx < end) ? __expf(x) : 0.f;

        for (int i = beg; i < end; ) {
            const int inext = i + SG;
            // phase 1 of next chunk: loads issue before this chunk's FMAs
            int u_n = 0; float w_n = 0.f;
            if (inext < end) {
                int idx2 = inext + q;
                int u2 = srcs[idx2 < end ? idx2 : end - 1];
                float x2 = el[(size_t)u2 * 4 + h] + ern;
                x2 = x2 > 0.f ? x2 : 0.2f * x2;
                w_n = (idx2 < end) ? __expf(x2) : 0.f;
                u_n = u2;
            }
            s += w_q;
            // phase 2: groups of 4 edges; all 4 gathers issue before FMAs
#pragma unroll
            for (int jj = 0; jj < SG; jj += 4) {
                int ub[4];
#pragma unroll
                for (int j = 0; j < 4; j++) ub[j] = __shfl(u_q, jj + j, SG);
                h8v fb[4];
#pragma unroll
                for (int j = 0; j < 4; j++) fb[j] = frow[(size_t)ub[j] * RSTR];
#pragma unroll
                for (int j = 0; j < 4; j += 2) {
                    float w0 = __shfl(w_q, jj + j, SG);
                    float w1 = __shfl(w_q, jj + j + 1, SG);
#pragma unroll
                    for (int k = 0; k < 8; k++) {
                        a0[k] += w0 * (float)fb[j][k];
                        a1[k] += w1 * (float)fb[j + 1][k];
                    }
                }
            }
            i = inext; u_q = u_n; w_q = w_n;
        }
    }
    // reduce s over the subgroup (each edge counted exactly once)
#pragma unroll
    for (int off = SG / 2; off >= 1; off >>= 1) s += __shfl_xor(s, off);
    const float inv = (s > 0.f) ? 1.f / s : 0.f;

    if constexpr (FP16OUT) {
        const float4 b0 = *reinterpret_cast<const float4*>(&bias[ln * 8]);
        const float4 b1v = *reinterpret_cast<const float4*>(&bias[ln * 8 + 4]);
        float bb[8] = {b0.x, b0.y, b0.z, b0.w, b1v.x, b1v.y, b1v.z, b1v.w};
        h8v o;
#pragma unroll
        for (int k = 0; k < 8; k++)
            o[k] = (_Float16)fmaxf((a0[k] + a1[k]) * inv + bb[k], 0.f);
        reinterpret_cast<h8v*>(outp)[(size_t)node * RSTR + ln] = o;
    } else {
        h8v o;                           // fp16 out, bias added in readout
#pragma unroll
        for (int k = 0; k < 8; k++) o[k] = (_Float16)((a0[k] + a1[k]) * inv);
        reinterpret_cast<h8v*>(outp)[(size_t)node * RSTR + ln] = o;
    }
}

// ---------------- batched-graph mean readout (two-phase, fp16 input) --------

__device__ __forceinline__ int lower_bound_i(const int* __restrict__ a, int n, int key) {
    int lo = 0, hi = n;
    while (lo < hi) {
        int mid = (lo + hi) >> 1;
        if (a[mid] < key) lo = mid + 1; else hi = mid;
    }
    return lo;
}

__global__ void readout_partial(const _Float16* __restrict__ agg, const int* __restrict__ gid,
                                float* __restrict__ part, int N, int C, int SL) {
    int g = blockIdx.x / SL, slice = blockIdx.x % SL;
    int c = threadIdx.x;
    int start = lower_bound_i(gid, N, g);
    int end = lower_bound_i(gid, N, g + 1);
    float sum = 0.f;
    for (int n = start + slice; n < end; n += SL) sum += (float)agg[(size_t)n * C + c];
    part[((size_t)g * SL + slice) * C + c] = sum;
}

__global__ void readout_final(const float* __restrict__ part, const float* __restrict__ b3,
                              const int* __restrict__ gid, float* __restrict__ out,
                              int N, int C, int SL) {
    int g = blockIdx.x, c = threadIdx.x;
    int start = lower_bound_i(gid, N, g);
    int end = lower_bound_i(gid, N, g + 1);
    int cnt = end - start;
    float s = 0.f;
    for (int k = 0; k < SL; k++) s += part[((size_t)g * SL + k) * C + c];
    out[(size_t)g * C + c] = (cnt > 0) ? s / (float)cnt + b3[c] : 0.f;
}

// ---------------- launch ----------------

extern "C" void kernel_launch(void* const* d_in, const int* in_sizes, int n_in,
                              void* d_out, int out_size, void* d_ws, size_t ws_size,
                              hipStream_t stream) {
    const float* feat0 = (const float*)d_in[0];
    const int* src = (const int*)d_in[1];
    const int* dst = (const int*)d_in[2];
    const int* gid = (const int*)d_in[3];
    const float* W1 = (const float*)d_in[4];
    const float* al1 = (const float*)d_in[5];
    const float* ar1 = (const float*)d_in[6];
    const float* b1 = (const float*)d_in[7];
    const float* W2 = (const float*)d_in[8];
    const float* al2 = (const float*)d_in[9];
    const float* ar2 = (const float*)d_in[10];
    const float* b2 = (const float*)d_in[11];
    const float* W3 = (const float*)d_in[12];
    const float* al3 = (const float*)d_in[13];
    const float* ar3 = (const float*)d_in[14];
    const float* b3 = (const float*)d_in[15];

    const int N = in_sizes[0] / 6;       // 30000
    const int E = in_sizes[1];           // 480000
    const int G = 64;
    const int SL = 16;
    float* out = (float*)d_out;

    char* wsp = (char*)d_ws;
    auto alloc = [&](size_t bytes) -> char* {
        char* p = wsp;
        wsp += (bytes + 255) & ~(size_t)255;
        return p;
    };
    int* counts   = (int*)alloc((size_t)N * 4);
    int* rowptrL  = (int*)alloc((size_t)(N + 1) * 4);
    int* rowptrG  = (int*)alloc((size_t)(N + 1) * 4);
    int* cursor   = (int*)alloc((size_t)N * 4);
    int* bsum     = (int*)alloc(64 * 4);
    int* srcs     = (int*)alloc((size_t)E * 4);
    float* el     = (float*)alloc((size_t)N * 4 * 4);
    float* er     = (float*)alloc((size_t)N * 4 * 4);
    _Float16* featH = (_Float16*)alloc((size_t)N * 256 * 2);  // GEMM out (gathered)
    _Float16* aggH  = (_Float16*)alloc((size_t)N * 128 * 2);  // activated agg out
    _Float16* aggF  = (_Float16*)alloc((size_t)N * 256 * 2);  // layer-3 agg (fp16)
    float* part   = (float*)alloc((size_t)G * SL * 256 * 4);
    _Float16* Wp2 = (_Float16*)alloc((size_t)128 * 128 * 2);
    _Float16* Wp3 = (_Float16*)alloc((size_t)128 * 256 * 2);

    const int nb = (N + 1023) / 1024;    // scan blocks (30)
    const int HB = (E + 255) / 256;      // hist blocks
    const int PB = 24;                   // pack blocks
    const int CB = (N + 63) / 64;        // layer-1 gemm blocks
    const int SB = (E + 255) / 256;      // scatter blocks
    const int AB = (N + 255) / 256;      // rowptrG finalize blocks

    // CSR build + front fusion
    zero_i32<<<dim3((N + 255) / 256), dim3(256), 0, stream>>>(counts, N);
    fused_front<<<dim3(HB + PB + CB), dim3(256), 0, stream>>>(
        dst, counts, E, W2, Wp2, W3, Wp3, feat0, W1, al1, ar1, featH, el, er, N, HB, PB);
    scan_block<<<dim3(nb), dim3(1024), 0, stream>>>(counts, rowptrL, bsum, cursor, N);
    scan_scatter<<<dim3(SB + AB), dim3(256), 0, stream>>>(
        rowptrL, bsum, rowptrG, src, dst, cursor, srcs, nb, N, E, SB);

    // layer 1 agg
    agg_sub<128, 32, true><<<dim3((N + 15) / 16), dim3(256), 0, stream>>>(
        (const h8v*)featH, el, er, srcs, rowptrG, b1, aggH, N);

    // layer 2
    gemm_mfma<128, 128, 32><<<dim3((N + 31) / 32), dim3(256), 0, stream>>>(
        aggH, Wp2, al2, ar2, featH, el, er, N);
    agg_sub<128, 32, true><<<dim3((N + 15) / 16), dim3(256), 0, stream>>>(
        (const h8v*)featH, el, er, srcs, rowptrG, b2, aggH, N);

    // layer 3
    gemm_mfma<128, 256, 64><<<dim3((N + 31) / 32), dim3(256), 0, stream>>>(
        aggH, Wp3, al3, ar3, featH, el, er, N);
    agg_sub<256, 64, false><<<dim3((N + 7) / 8), dim3(256), 0, stream>>>(
        (const h8v*)featH, el, er, srcs, rowptrG, nullptr, aggF, N);

    // readout (fp16 in, bias fp32 in final)
    readout_partial<<<dim3(G * SL), dim3(256), 0, stream>>>(aggF, gid, part, N, 256, SL);
    readout_final<<<dim3(G), dim3(256), 0, stream>>>(part, b3, gid, out, N, 256, SL);
}